// Round 1
// baseline (149.396 us; speedup 1.0000x reference)
//
#include <hip/hip_runtime.h>
#include <math.h>

#define BSZ 4
#define SSZ 1024
#define EMBD 128
#define HN 4
#define DN 32
#define TQ (SSZ - 1)      // 1023 queries per batch
#define NROWS (BSZ * TQ)  // 4092

typedef __attribute__((ext_vector_type(8))) short bf16x8;
typedef __attribute__((ext_vector_type(4))) short bf16x4;
typedef __attribute__((ext_vector_type(4))) float f32x4;

static __device__ __forceinline__ unsigned short f2bf(float x) {
    union { float f; unsigned u; } v; v.f = x;
    unsigned r = v.u + 0x7fffu + ((v.u >> 16) & 1u);   // RNE
    return (unsigned short)(r >> 16);
}
static __device__ __forceinline__ bf16x8 cvt8(const float4 a, const float4 b) {
    bf16x8 v;
    v[0] = (short)f2bf(a.x); v[1] = (short)f2bf(a.y);
    v[2] = (short)f2bf(a.z); v[3] = (short)f2bf(a.w);
    v[4] = (short)f2bf(b.x); v[5] = (short)f2bf(b.y);
    v[6] = (short)f2bf(b.z); v[7] = (short)f2bf(b.w);
    return v;
}

// ---------------------------------------------------------------------------
// Kernel 1: embed + project via MFMA, pipelined weight staging.
// Block = 16 tokens, 256 threads, wave w = head w.
// 20 weight-chunk rounds: r<8 Wh (A=e then a), 8..11 Wq, 12..15 Wk, 16..19 Wv.
// Chunk r+1 is prefetched into registers during round r's MFMAs.
// Outputs Q(bf16, xscale), K(bf16), V(bf16) in [bh][s][d]; ec fp32; sr fp32.
// ---------------------------------------------------------------------------
__global__ __launch_bounds__(256)
void embed4_kernel(const int* __restrict__ idx, const int* __restrict__ flg,
                   const float* __restrict__ item_emb, const float* __restrict__ ans_emb,
                   const float* __restrict__ Wq, const float* __restrict__ bq,
                   const float* __restrict__ Wk, const float* __restrict__ bk,
                   const float* __restrict__ Wv, const float* __restrict__ bv,
                   const float* __restrict__ Wh, const float* __restrict__ bh_bias,
                   unsigned short* __restrict__ Qts, unsigned short* __restrict__ Kts,
                   unsigned short* __restrict__ Vts,
                   float* __restrict__ ec, float* __restrict__ srw)
{
    __shared__ __align__(16) unsigned short esb[16][136];
    __shared__ __align__(16) unsigned short asb[16][136];
    __shared__ __align__(16) unsigned short intb[16][136];
    __shared__ __align__(16) unsigned short Wt[128][40];

    const int tid = threadIdx.x;
    const int tok0 = blockIdx.x * 16;
    const int b = blockIdx.x >> 6;
    const int s0 = tok0 & 1023;
    const int w = tid >> 6, lane = tid & 63;
    const int quad = lane >> 4, col = lane & 15;

    // ---- stage e, a (bf16) + ec (fp32) ----
    {
        const int tk = tid >> 4;
        const int d0 = (tid & 15) * 8;
        const int tok = tok0 + tk;
        const float* esrc = item_emb + (size_t)idx[tok] * EMBD + d0;
        const float* asrc = ans_emb + (size_t)flg[tok] * EMBD + d0;
        const float4 e0 = *(const float4*)esrc;
        const float4 e1 = *(const float4*)(esrc + 4);
        const float4 a0 = *(const float4*)asrc;
        const float4 a1 = *(const float4*)(asrc + 4);
        *(float4*)(ec + (size_t)tok * EMBD + d0) = e0;
        *(float4*)(ec + (size_t)tok * EMBD + d0 + 4) = e1;
        *(bf16x8*)&esb[tk][d0] = cvt8(e0, e1);
        *(bf16x8*)&asb[tk][d0] = cvt8(a0, a1);
    }

    const int jb = (tid & 31) * 4;
    const int ib = (tid >> 5) * 4;
    float rr[4][4];

    #define WSRC(R) ((R) < 8 ? Wh + (size_t)(R) * 4096                     \
                  : (R) < 12 ? Wq + (size_t)((R) - 8) * 4096               \
                  : (R) < 16 ? Wk + (size_t)((R) - 12) * 4096              \
                  : Wv + (size_t)((R) - 16) * 4096)
    #define LOADW(P)                                                       \
    {                                                                      \
        const float* _p = (P);                                             \
        *(float4*)rr[0] = *(const float4*)(_p + (ib + 0) * 128 + jb);      \
        *(float4*)rr[1] = *(const float4*)(_p + (ib + 1) * 128 + jb);      \
        *(float4*)rr[2] = *(const float4*)(_p + (ib + 2) * 128 + jb);      \
        *(float4*)rr[3] = *(const float4*)(_p + (ib + 3) * 128 + jb);      \
    }
    #define STOREW                                                         \
    {                                                                      \
        _Pragma("unroll")                                                  \
        for (int jj = 0; jj < 4; jj++) {                                   \
            bf16x4 v;                                                      \
            v[0] = (short)f2bf(rr[0][jj]); v[1] = (short)f2bf(rr[1][jj]);  \
            v[2] = (short)f2bf(rr[2][jj]); v[3] = (short)f2bf(rr[3][jj]);  \
            *(bf16x4*)&Wt[jb + jj][ib] = v;                                \
        }                                                                  \
    }

    f32x4 accI[2] = {{0.f,0.f,0.f,0.f},{0.f,0.f,0.f,0.f}};
    f32x4 accQ[2] = {{0.f,0.f,0.f,0.f},{0.f,0.f,0.f,0.f}};
    f32x4 accK[2] = {{0.f,0.f,0.f,0.f},{0.f,0.f,0.f,0.f}};
    f32x4 accV[2] = {{0.f,0.f,0.f,0.f},{0.f,0.f,0.f,0.f}};

    LOADW(WSRC(0));
    #pragma unroll
    for (int r = 0; r < 20; r++) {
        __syncthreads();
        STOREW;
        __syncthreads();
        if (r < 19) LOADW(WSRC(r + 1));        // prefetch next chunk (overlaps MFMA)

        const unsigned short (*Ab)[136] = (r < 4) ? esb : (r < 8) ? asb
                                        : (r < 16) ? esb : intb;
        const int koff = ((r < 8) ? (r & 3) : (r < 12) ? (r - 8)
                        : (r < 16) ? (r - 12) : (r - 16)) * 32;
        const bf16x8 af = *(const bf16x8*)&Ab[col][koff + quad * 8];
        f32x4* acc = (r < 8) ? accI : (r < 12) ? accQ : (r < 16) ? accK : accV;
        #pragma unroll
        for (int ntl = 0; ntl < 2; ntl++) {
            const bf16x8 bf = *(const bf16x8*)&Wt[w * 32 + ntl * 16 + col][quad * 8];
            acc[ntl] = __builtin_amdgcn_mfma_f32_16x16x32_bf16(af, bf, acc[ntl], 0, 0, 0);
        }
        if (r == 7) {   // inter ready -> intb (visible via round-8 barriers)
            #pragma unroll
            for (int ntl = 0; ntl < 2; ntl++) {
                const int j = w * 32 + ntl * 16 + col;
                const float bb = bh_bias[j];
                #pragma unroll
                for (int r4 = 0; r4 < 4; r4++)
                    intb[quad * 4 + r4][j] = f2bf(accI[ntl][r4] + bb);
            }
        }
    }
    #undef LOADW
    #undef STOREW
    #undef WSRC

    // ---- epilogue: biases, sr, bf16 stores ----
    const int bhn = b * HN + w;
    const float scale = 0.17677669529663687f;
    float p[4] = {0.f, 0.f, 0.f, 0.f};
    #pragma unroll
    for (int ntl = 0; ntl < 2; ntl++) {
        const int j = w * 32 + ntl * 16 + col;
        const float bQ = bq[j], bK = bk[j], bV = bv[j];
        #pragma unroll
        for (int r = 0; r < 4; r++) {
            const float qv = accQ[ntl][r] + bQ;
            const float kv = accK[ntl][r] + bK;
            const int s = s0 + quad * 4 + r;
            const size_t o = ((size_t)bhn * SSZ + s) * DN + ntl * 16 + col;
            Qts[o] = f2bf(qv * scale);
            Kts[o] = f2bf(kv);
            Vts[o] = f2bf(accV[ntl][r] + bV);
            p[r] = fmaf(qv, kv, p[r]);
        }
    }
    #pragma unroll
    for (int r = 0; r < 4; r++) {
        float pr = p[r];
        pr += __shfl_xor(pr, 1, 64);
        pr += __shfl_xor(pr, 2, 64);
        pr += __shfl_xor(pr, 4, 64);
        pr += __shfl_xor(pr, 8, 64);
        if (col == 0)
            srw[(size_t)bhn * SSZ + s0 + quad * 4 + r] = pr * scale;
    }
}

// ---------------------------------------------------------------------------
// Kernel 2: fused scan + MFMA attention. Block = (bh, qtile of 64). 4 waves.
// Phase 0: in-block Ep = cumsum(exp(sr)) (max cancels in the rel ratio) and
// Pp = cumsum(max(gaps,1)) via wave scans. Then flash loop with K/V register
// prefetch (chunk c+1 loads overlap chunk c compute).
// ---------------------------------------------------------------------------
__global__ __launch_bounds__(256)
void attn4_kernel(const unsigned short* __restrict__ Qts,
                  const unsigned short* __restrict__ Kts,
                  const unsigned short* __restrict__ Vts,
                  const float* __restrict__ srw, const float* __restrict__ gaps,
                  const float* __restrict__ theta_raw, float* __restrict__ csw)
{
    __shared__ __align__(16) unsigned short Ks[64][40];
    __shared__ __align__(16) unsigned short Vs[32][72];
    __shared__ __align__(16) unsigned short Ps[4][16][72];
    __shared__ float EpS[SSZ + 1];
    __shared__ float PpS[SSZ + 1];
    __shared__ float wtot[4];

    const int bid = blockIdx.x;        // bh*16 + qt
    const int qt = bid & 15;
    const int bh = bid >> 4;
    const int b = bh >> 2, h = bh & 3;
    const int tid = threadIdx.x;
    const int w = tid >> 6, lane = tid & 63;
    const int quad = lane >> 4, col = lane & 15;
    const int t0 = qt * 64 + 1;

    // ---- phase 0a: Ep scan (1024 elems, 4/thread) ----
    {
        const float4 sv = *(const float4*)(srw + (size_t)bh * SSZ + tid * 4);
        const float e0 = __expf(sv.x);
        const float p0 = e0;
        const float p1 = p0 + __expf(sv.y);
        const float p2 = p1 + __expf(sv.z);
        const float p3 = p2 + __expf(sv.w);
        float s = p3;
        #pragma unroll
        for (int d = 1; d < 64; d <<= 1) {
            const float t = __shfl_up(s, d, 64);
            if (lane >= d) s += t;
        }
        if (lane == 63) wtot[w] = s;
        __syncthreads();
        float base = s - p3;
        for (int ww = 0; ww < w; ww++) base += wtot[ww];
        EpS[tid * 4 + 1] = base + p0;
        EpS[tid * 4 + 2] = base + p1;
        EpS[tid * 4 + 3] = base + p2;
        EpS[tid * 4 + 4] = base + p3;
        if (tid == 0) EpS[0] = 0.0f;
    }
    // ---- phase 0b: Pp scan ----
    {
        const float4 gv = *(const float4*)(gaps + (size_t)b * SSZ + tid * 4);
        const float p0 = fmaxf(gv.x, 1.0f);
        const float p1 = p0 + fmaxf(gv.y, 1.0f);
        const float p2 = p1 + fmaxf(gv.z, 1.0f);
        const float p3 = p2 + fmaxf(gv.w, 1.0f);
        float s = p3;
        #pragma unroll
        for (int d = 1; d < 64; d <<= 1) {
            const float t = __shfl_up(s, d, 64);
            if (lane >= d) s += t;
        }
        __syncthreads();               // all wtot reads from 0a done
        if (lane == 63) wtot[w] = s;
        __syncthreads();
        float base = s - p3;
        for (int ww = 0; ww < w; ww++) base += wtot[ww];
        PpS[tid * 4 + 1] = base + p0;
        PpS[tid * 4 + 2] = base + p1;
        PpS[tid * 4 + 3] = base + p2;
        PpS[tid * 4 + 4] = base + p3;
        if (tid == 0) PpS[0] = 0.0f;
    }
    __syncthreads();

    // ---- per-lane invariants ----
    const float theta = logf(1.0f + __expf(theta_raw[h])) + 1e-4f;
    const float nth = -theta;
    float Ept[4], Ppt[4], iEp[4], tft[4];
    int qrow[4], tq[4];
    #pragma unroll
    for (int r = 0; r < 4; r++) {
        qrow[r] = w * 16 + quad * 4 + r;
        tq[r] = t0 + qrow[r];
        tft[r] = (float)tq[r];
        Ept[r] = EpS[tq[r]];
        Ppt[r] = PpS[tq[r]];
        iEp[r] = 1.0f / Ept[r];
    }

    // ---- Q A-frag direct from global (bf16, pre-scaled) ----
    bf16x8 aq;
    {
        int t = t0 + w * 16 + col; if (t > 1023) t = 1023;
        aq = *(const bf16x8*)(Qts + ((size_t)(bh * SSZ + t)) * DN + quad * 8);
    }

    f32x4 acc0 = {0.f, 0.f, 0.f, 0.f};
    f32x4 acc1 = {0.f, 0.f, 0.f, 0.f};
    float lsum[4] = {0.f, 0.f, 0.f, 0.f};

    const int i_st = tid >> 2;
    const int d0 = (tid & 3) * 8;
    bf16x8 kreg = *(const bf16x8*)(Kts + ((size_t)(bh * SSZ + i_st)) * DN + d0);
    bf16x8 vreg = *(const bf16x8*)(Vts + ((size_t)(bh * SSZ + i_st)) * DN + d0);

    for (int c = 0; c <= qt; c++) {
        __syncthreads();               // previous chunk consumed
        *(bf16x8*)&Ks[i_st][d0] = kreg;
        #pragma unroll
        for (int k2 = 0; k2 < 8; k2++) Vs[d0 + k2][i_st] = (unsigned short)vreg[k2];
        __syncthreads();
        if (c < qt) {                  // prefetch next chunk (overlaps compute)
            const size_t o = ((size_t)(bh * SSZ + (c + 1) * 64 + i_st)) * DN + d0;
            kreg = *(const bf16x8*)(Kts + o);
            vreg = *(const bf16x8*)(Vts + o);
        }

        const bool full = (c < qt);
        #pragma unroll
        for (int nt = 0; nt < 4; nt++) {
            const bf16x8 bk = *(const bf16x8*)&Ks[nt * 16 + col][quad * 8];
            f32x4 z = {0.f, 0.f, 0.f, 0.f};
            f32x4 raw = __builtin_amdgcn_mfma_f32_16x16x32_bf16(aq, bk, z, 0, 0, 0);
            const int il = nt * 16 + col;
            const int i_ = c * 64 + il;
            const float Epi = EpS[i_];
            const float Ppi = PpS[i_];
            const float fi = (float)i_;
            #pragma unroll
            for (int r = 0; r < 4; r++) {
                const float pdv = (tft[r] - fi) * (Ppt[r] - Ppi) * ((Ept[r] - Epi) * iEp[r]);
                const float sc  = raw[r] * __expf(nth * pdv);
                float p = __expf(sc);
                p = (full || il <= qrow[r]) ? p : 0.0f;
                lsum[r] += p;
                Ps[w][quad * 4 + r][il] = f2bf(p);
            }
        }
        #pragma unroll
        for (int ks = 0; ks < 2; ks++) {
            const bf16x8 ap = *(const bf16x8*)&Ps[w][col][ks * 32 + quad * 8];
            const bf16x8 bv0 = *(const bf16x8*)&Vs[col][ks * 32 + quad * 8];
            const bf16x8 bv1 = *(const bf16x8*)&Vs[16 + col][ks * 32 + quad * 8];
            acc0 = __builtin_amdgcn_mfma_f32_16x16x32_bf16(ap, bv0, acc0, 0, 0, 0);
            acc1 = __builtin_amdgcn_mfma_f32_16x16x32_bf16(ap, bv1, acc1, 0, 0, 0);
        }
    }

    #pragma unroll
    for (int r = 0; r < 4; r++) {
        float lr = lsum[r];
        #pragma unroll
        for (int msk = 8; msk >= 1; msk >>= 1) lr += __shfl_xor(lr, msk, 64);
        lsum[r] = 1.0f / lr;
    }
    #pragma unroll
    for (int r = 0; r < 4; r++) {
        if (tq[r] <= 1023) {
            float* dst = csw + ((size_t)(b * TQ + (tq[r] - 1))) * EMBD + h * DN;
            dst[col]      = acc0[r] * lsum[r];
            dst[16 + col] = acc1[r] * lsum[r];
        }
    }
}

// ---------------------------------------------------------------------------
// Kernel 3: MLP via MFMA (unchanged from R6).
// ---------------------------------------------------------------------------
__global__ __launch_bounds__(256)
void mlp3_kernel(const float* __restrict__ csw, const float* __restrict__ ec,
                 const float* __restrict__ W1, const float* __restrict__ b1,
                 const float* __restrict__ W2, const float* __restrict__ b2,
                 float* __restrict__ out)
{
    __shared__ __align__(16) unsigned short featb[32][264];
    __shared__ __align__(16) unsigned short W1t[128][264];
    __shared__ float sred[4][16];

    const int tid = threadIdx.x;
    const int r0 = blockIdx.x * 32;
    const int w = tid >> 6, lane = tid & 63;
    const int quad = lane >> 4, col = lane & 15;
    const int mt = w & 1, nh = w >> 1;

    {
        const int jb = (tid & 31) * 4;
        const int ib = (tid >> 5) * 4;
        for (int ic = 0; ic < 8; ic++) {
            const int i0 = ic * 32 + ib;
            float rr[4][4];
            *(float4*)rr[0] = *(const float4*)(W1 + (size_t)(i0 + 0) * 128 + jb);
            *(float4*)rr[1] = *(const float4*)(W1 + (size_t)(i0 + 1) * 128 + jb);
            *(float4*)rr[2] = *(const float4*)(W1 + (size_t)(i0 + 2) * 128 + jb);
            *(float4*)rr[3] = *(const float4*)(W1 + (size_t)(i0 + 3) * 128 + jb);
            #pragma unroll
            for (int jj = 0; jj < 4; jj++) {
                bf16x4 v;
                v[0] = (short)f2bf(rr[0][jj]); v[1] = (short)f2bf(rr[1][jj]);
                v[2] = (short)f2bf(rr[2][jj]); v[3] = (short)f2bf(rr[3][jj]);
                *(bf16x4*)&W1t[jb + jj][i0] = v;
            }
        }
    }
    {
        const int rr = tid >> 3;
        const int c0 = (tid & 7) * 32;
        int row = r0 + rr; if (row >= NROWS) row = NROWS - 1;
        const float* src;
        if (c0 < 128) {
            src = csw + (size_t)row * EMBD + c0;
        } else {
            const int bb = row / TQ;
            const int tt = row - bb * TQ + 1;
            src = ec + ((size_t)(bb * SSZ + tt)) * EMBD + (c0 - 128);
        }
        #pragma unroll
        for (int g = 0; g < 4; g++) {
            const float4 f0 = ((const float4*)src)[g * 2];
            const float4 f1 = ((const float4*)src)[g * 2 + 1];
            *(bf16x8*)&featb[rr][c0 + g * 8] = cvt8(f0, f1);
        }
    }
    __syncthreads();

    float s[4] = {0.f, 0.f, 0.f, 0.f};
    #pragma unroll
    for (int ntl = 0; ntl < 4; ntl++) {
        const int nt = nh * 4 + ntl;
        f32x4 acc = {0.f, 0.f, 0.f, 0.f};
        #pragma unroll
        for (int kc = 0; kc < 8; kc++) {
            const bf16x8 af = *(const bf16x8*)&featb[mt * 16 + col][kc * 32 + quad * 8];
            const bf16x8 bf = *(const bf16x8*)&W1t[nt * 16 + col][kc * 32 + quad * 8];
            acc = __builtin_amdgcn_mfma_f32_16x16x32_bf16(af, bf, acc, 0, 0, 0);
        }
        const int j = nt * 16 + col;
        const float b1j = b1[j], w2j = W2[j];
        #pragma unroll
        for (int r = 0; r < 4; r++)
            s[r] = fmaf(fmaxf(acc[r] + b1j, 0.0f), w2j, s[r]);
    }
    #pragma unroll
    for (int r = 0; r < 4; r++) {
        float sr = s[r];
        sr += __shfl_xor(sr, 1, 64);
        sr += __shfl_xor(sr, 2, 64);
        sr += __shfl_xor(sr, 4, 64);
        sr += __shfl_xor(sr, 8, 64);
        if (col == 0) sred[w][quad * 4 + r] = sr;
    }
    __syncthreads();
    if (tid < 32) {
        const int mt2 = tid >> 4, rr = tid & 15;
        const float logit = sred[mt2][rr] + sred[mt2 + 2][rr] + b2[0];
        const int grow = r0 + tid;
        if (grow < NROWS) {
            out[grow] = 1.0f / (1.0f + __expf(-logit));
            out[NROWS + grow] = 1.0f;
        }
    }
}

// ---------------------------------------------------------------------------
extern "C" void kernel_launch(void* const* d_in, const int* in_sizes, int n_in,
                              void* d_out, int out_size, void* d_ws, size_t ws_size,
                              hipStream_t stream)
{
    const int*   idx       = (const int*)d_in[0];
    const int*   flg       = (const int*)d_in[1];
    const float* gaps      = (const float*)d_in[2];
    const float* item_emb  = (const float*)d_in[3];
    const float* ans_emb   = (const float*)d_in[4];
    const float* Wq        = (const float*)d_in[5];
    const float* bq        = (const float*)d_in[6];
    const float* Wk        = (const float*)d_in[7];
    const float* bk        = (const float*)d_in[8];
    const float* Wv        = (const float*)d_in[9];
    const float* bv        = (const float*)d_in[10];
    const float* Wh        = (const float*)d_in[11];
    const float* bh        = (const float*)d_in[12];
    const float* W1        = (const float*)d_in[13];
    const float* b1        = (const float*)d_in[14];
    const float* W2        = (const float*)d_in[15];
    const float* b2        = (const float*)d_in[16];
    const float* theta_raw = (const float*)d_in[17];
    (void)in_sizes; (void)n_in; (void)ws_size;

    const size_t QKV = (size_t)BSZ * HN * SSZ * DN;   // 524288 elements
    unsigned short* Qts = (unsigned short*)d_ws;
    unsigned short* Kts = Qts + QKV;
    unsigned short* Vts = Kts + QKV;
    float* ec  = (float*)(Vts + QKV);                 // 3 MB offset, aligned
    float* srw = ec + (size_t)BSZ * SSZ * EMBD;
    float* csw = srw + (size_t)BSZ * HN * SSZ;

    float* out = (float*)d_out;

    embed4_kernel<<<BSZ * SSZ / 16, 256, 0, stream>>>(
        idx, flg, item_emb, ans_emb, Wq, bq, Wk, bk, Wv, bv, Wh, bh,
        Qts, Kts, Vts, ec, srw);
    attn4_kernel<<<BSZ * HN * 16, 256, 0, stream>>>(
        Qts, Kts, Vts, srw, gaps, theta_raw, csw);
    mlp3_kernel<<<(NROWS + 31) / 32, 256, 0, stream>>>(
        csw, ec, W1, b1, W2, b2, out);
}

// Round 2
// 144.791 us; speedup vs baseline: 1.0318x; 1.0318x over previous
//
#include <hip/hip_runtime.h>
#include <math.h>

#define BSZ 4
#define SSZ 1024
#define EMBD 128
#define HN 4
#define DN 32
#define TQ (SSZ - 1)      // 1023 queries per batch
#define NROWS (BSZ * TQ)  // 4092

typedef __attribute__((ext_vector_type(8))) short bf16x8;
typedef __attribute__((ext_vector_type(4))) short bf16x4;
typedef __attribute__((ext_vector_type(4))) float f32x4;

static __device__ __forceinline__ unsigned short f2bf(float x) {
    union { float f; unsigned u; } v; v.f = x;
    unsigned r = v.u + 0x7fffu + ((v.u >> 16) & 1u);   // RNE
    return (unsigned short)(r >> 16);
}
static __device__ __forceinline__ bf16x8 cvt8(const float4 a, const float4 b) {
    bf16x8 v;
    v[0] = (short)f2bf(a.x); v[1] = (short)f2bf(a.y);
    v[2] = (short)f2bf(a.z); v[3] = (short)f2bf(a.w);
    v[4] = (short)f2bf(b.x); v[5] = (short)f2bf(b.y);
    v[6] = (short)f2bf(b.z); v[7] = (short)f2bf(b.w);
    return v;
}

// ---------------------------------------------------------------------------
// Kernel 1: embed + project via MFMA, pipelined weight staging. (unchanged)
// ---------------------------------------------------------------------------
__global__ __launch_bounds__(256)
void embed4_kernel(const int* __restrict__ idx, const int* __restrict__ flg,
                   const float* __restrict__ item_emb, const float* __restrict__ ans_emb,
                   const float* __restrict__ Wq, const float* __restrict__ bq,
                   const float* __restrict__ Wk, const float* __restrict__ bk,
                   const float* __restrict__ Wv, const float* __restrict__ bv,
                   const float* __restrict__ Wh, const float* __restrict__ bh_bias,
                   unsigned short* __restrict__ Qts, unsigned short* __restrict__ Kts,
                   unsigned short* __restrict__ Vts,
                   float* __restrict__ ec, float* __restrict__ srw)
{
    __shared__ __align__(16) unsigned short esb[16][136];
    __shared__ __align__(16) unsigned short asb[16][136];
    __shared__ __align__(16) unsigned short intb[16][136];
    __shared__ __align__(16) unsigned short Wt[128][40];

    const int tid = threadIdx.x;
    const int tok0 = blockIdx.x * 16;
    const int b = blockIdx.x >> 6;
    const int s0 = tok0 & 1023;
    const int w = tid >> 6, lane = tid & 63;
    const int quad = lane >> 4, col = lane & 15;

    // ---- stage e, a (bf16) + ec (fp32) ----
    {
        const int tk = tid >> 4;
        const int d0 = (tid & 15) * 8;
        const int tok = tok0 + tk;
        const float* esrc = item_emb + (size_t)idx[tok] * EMBD + d0;
        const float* asrc = ans_emb + (size_t)flg[tok] * EMBD + d0;
        const float4 e0 = *(const float4*)esrc;
        const float4 e1 = *(const float4*)(esrc + 4);
        const float4 a0 = *(const float4*)asrc;
        const float4 a1 = *(const float4*)(asrc + 4);
        *(float4*)(ec + (size_t)tok * EMBD + d0) = e0;
        *(float4*)(ec + (size_t)tok * EMBD + d0 + 4) = e1;
        *(bf16x8*)&esb[tk][d0] = cvt8(e0, e1);
        *(bf16x8*)&asb[tk][d0] = cvt8(a0, a1);
    }

    const int jb = (tid & 31) * 4;
    const int ib = (tid >> 5) * 4;
    float rr[4][4];

    #define WSRC(R) ((R) < 8 ? Wh + (size_t)(R) * 4096                     \
                  : (R) < 12 ? Wq + (size_t)((R) - 8) * 4096               \
                  : (R) < 16 ? Wk + (size_t)((R) - 12) * 4096              \
                  : Wv + (size_t)((R) - 16) * 4096)
    #define LOADW(P)                                                       \
    {                                                                      \
        const float* _p = (P);                                             \
        *(float4*)rr[0] = *(const float4*)(_p + (ib + 0) * 128 + jb);      \
        *(float4*)rr[1] = *(const float4*)(_p + (ib + 1) * 128 + jb);      \
        *(float4*)rr[2] = *(const float4*)(_p + (ib + 2) * 128 + jb);      \
        *(float4*)rr[3] = *(const float4*)(_p + (ib + 3) * 128 + jb);      \
    }
    #define STOREW                                                         \
    {                                                                      \
        _Pragma("unroll")                                                  \
        for (int jj = 0; jj < 4; jj++) {                                   \
            bf16x4 v;                                                      \
            v[0] = (short)f2bf(rr[0][jj]); v[1] = (short)f2bf(rr[1][jj]);  \
            v[2] = (short)f2bf(rr[2][jj]); v[3] = (short)f2bf(rr[3][jj]);  \
            *(bf16x4*)&Wt[jb + jj][ib] = v;                                \
        }                                                                  \
    }

    f32x4 accI[2] = {{0.f,0.f,0.f,0.f},{0.f,0.f,0.f,0.f}};
    f32x4 accQ[2] = {{0.f,0.f,0.f,0.f},{0.f,0.f,0.f,0.f}};
    f32x4 accK[2] = {{0.f,0.f,0.f,0.f},{0.f,0.f,0.f,0.f}};
    f32x4 accV[2] = {{0.f,0.f,0.f,0.f},{0.f,0.f,0.f,0.f}};

    LOADW(WSRC(0));
    #pragma unroll
    for (int r = 0; r < 20; r++) {
        __syncthreads();
        STOREW;
        __syncthreads();
        if (r < 19) LOADW(WSRC(r + 1));        // prefetch next chunk (overlaps MFMA)

        const unsigned short (*Ab)[136] = (r < 4) ? esb : (r < 8) ? asb
                                        : (r < 16) ? esb : intb;
        const int koff = ((r < 8) ? (r & 3) : (r < 12) ? (r - 8)
                        : (r < 16) ? (r - 12) : (r - 16)) * 32;
        const bf16x8 af = *(const bf16x8*)&Ab[col][koff + quad * 8];
        f32x4* acc = (r < 8) ? accI : (r < 12) ? accQ : (r < 16) ? accK : accV;
        #pragma unroll
        for (int ntl = 0; ntl < 2; ntl++) {
            const bf16x8 bf = *(const bf16x8*)&Wt[w * 32 + ntl * 16 + col][quad * 8];
            acc[ntl] = __builtin_amdgcn_mfma_f32_16x16x32_bf16(af, bf, acc[ntl], 0, 0, 0);
        }
        if (r == 7) {   // inter ready -> intb (visible via round-8 barriers)
            #pragma unroll
            for (int ntl = 0; ntl < 2; ntl++) {
                const int j = w * 32 + ntl * 16 + col;
                const float bb = bh_bias[j];
                #pragma unroll
                for (int r4 = 0; r4 < 4; r4++)
                    intb[quad * 4 + r4][j] = f2bf(accI[ntl][r4] + bb);
            }
        }
    }
    #undef LOADW
    #undef STOREW
    #undef WSRC

    // ---- epilogue: biases, sr, bf16 stores ----
    const int bhn = b * HN + w;
    const float scale = 0.17677669529663687f;
    float p[4] = {0.f, 0.f, 0.f, 0.f};
    #pragma unroll
    for (int ntl = 0; ntl < 2; ntl++) {
        const int j = w * 32 + ntl * 16 + col;
        const float bQ = bq[j], bK = bk[j], bV = bv[j];
        #pragma unroll
        for (int r = 0; r < 4; r++) {
            const float qv = accQ[ntl][r] + bQ;
            const float kv = accK[ntl][r] + bK;
            const int s = s0 + quad * 4 + r;
            const size_t o = ((size_t)bhn * SSZ + s) * DN + ntl * 16 + col;
            Qts[o] = f2bf(qv * scale);
            Kts[o] = f2bf(kv);
            Vts[o] = f2bf(accV[ntl][r] + bV);
            p[r] = fmaf(qv, kv, p[r]);
        }
    }
    #pragma unroll
    for (int r = 0; r < 4; r++) {
        float pr = p[r];
        pr += __shfl_xor(pr, 1, 64);
        pr += __shfl_xor(pr, 2, 64);
        pr += __shfl_xor(pr, 4, 64);
        pr += __shfl_xor(pr, 8, 64);
        if (col == 0)
            srw[(size_t)bhn * SSZ + s0 + quad * 4 + r] = pr * scale;
    }
}

// ---------------------------------------------------------------------------
// Kernel 2: fused scan + MFMA attention, KV-SPLIT.
// Block = (bh, qtile of 64, half). Grid 512 = 2 blocks/CU.
// Each half computes a contiguous sub-range of the chunk loop and writes
// UNNORMALIZED partial acc (fp32) + partial lsum; mlp3 combines:
// ctx = (acc0+acc1) / (l0+l1). Partials are exactly additive because the
// softmax uses un-shifted exp. Diagonal (masked) chunk always in half 1.
// Critical path: 16 chunks -> 8.
// ---------------------------------------------------------------------------
__global__ __launch_bounds__(256)
void attn4_kernel(const unsigned short* __restrict__ Qts,
                  const unsigned short* __restrict__ Kts,
                  const unsigned short* __restrict__ Vts,
                  const float* __restrict__ srw, const float* __restrict__ gaps,
                  const float* __restrict__ theta_raw, float* __restrict__ csw,
                  float* __restrict__ ls)
{
    __shared__ __align__(16) unsigned short Ks[64][40];
    __shared__ __align__(16) unsigned short Vs[32][72];
    __shared__ __align__(16) unsigned short Ps[4][16][72];
    __shared__ float EpS[SSZ + 1];
    __shared__ float PpS[SSZ + 1];
    __shared__ float wtot[4];

    const int bid = blockIdx.x;        // bh*32 + qt*2 + half
    const int half = bid & 1;
    const int qt = (bid >> 1) & 15;
    const int bh = bid >> 5;
    const int b = bh >> 2, h = bh & 3;
    const int tid = threadIdx.x;
    const int w = tid >> 6, lane = tid & 63;
    const int quad = lane >> 4, col = lane & 15;
    const int t0 = qt * 64 + 1;

    // chunk sub-range [c0r, c1r)
    const int nc = qt + 1;
    const int c0r = half ? (nc >> 1) : 0;
    const int c1r = half ? nc : (nc >> 1);

    // ---- phase 0a: Ep scan (1024 elems, 4/thread) ----
    {
        const float4 sv = *(const float4*)(srw + (size_t)bh * SSZ + tid * 4);
        const float e0 = __expf(sv.x);
        const float p0 = e0;
        const float p1 = p0 + __expf(sv.y);
        const float p2 = p1 + __expf(sv.z);
        const float p3 = p2 + __expf(sv.w);
        float s = p3;
        #pragma unroll
        for (int d = 1; d < 64; d <<= 1) {
            const float t = __shfl_up(s, d, 64);
            if (lane >= d) s += t;
        }
        if (lane == 63) wtot[w] = s;
        __syncthreads();
        float base = s - p3;
        for (int ww = 0; ww < w; ww++) base += wtot[ww];
        EpS[tid * 4 + 1] = base + p0;
        EpS[tid * 4 + 2] = base + p1;
        EpS[tid * 4 + 3] = base + p2;
        EpS[tid * 4 + 4] = base + p3;
        if (tid == 0) EpS[0] = 0.0f;
    }
    // ---- phase 0b: Pp scan ----
    {
        const float4 gv = *(const float4*)(gaps + (size_t)b * SSZ + tid * 4);
        const float p0 = fmaxf(gv.x, 1.0f);
        const float p1 = p0 + fmaxf(gv.y, 1.0f);
        const float p2 = p1 + fmaxf(gv.z, 1.0f);
        const float p3 = p2 + fmaxf(gv.w, 1.0f);
        float s = p3;
        #pragma unroll
        for (int d = 1; d < 64; d <<= 1) {
            const float t = __shfl_up(s, d, 64);
            if (lane >= d) s += t;
        }
        __syncthreads();               // all wtot reads from 0a done
        if (lane == 63) wtot[w] = s;
        __syncthreads();
        float base = s - p3;
        for (int ww = 0; ww < w; ww++) base += wtot[ww];
        PpS[tid * 4 + 1] = base + p0;
        PpS[tid * 4 + 2] = base + p1;
        PpS[tid * 4 + 3] = base + p2;
        PpS[tid * 4 + 4] = base + p3;
        if (tid == 0) PpS[0] = 0.0f;
    }
    __syncthreads();

    // ---- per-lane invariants ----
    const float theta = logf(1.0f + __expf(theta_raw[h])) + 1e-4f;
    const float nth = -theta;
    float Ept[4], Ppt[4], iEp[4], tft[4];
    int qrow[4], tq[4];
    #pragma unroll
    for (int r = 0; r < 4; r++) {
        qrow[r] = w * 16 + quad * 4 + r;
        tq[r] = t0 + qrow[r];
        tft[r] = (float)tq[r];
        Ept[r] = EpS[tq[r]];
        Ppt[r] = PpS[tq[r]];
        iEp[r] = 1.0f / Ept[r];
    }

    // ---- Q A-frag direct from global (bf16, pre-scaled) ----
    bf16x8 aq;
    {
        int t = t0 + w * 16 + col; if (t > 1023) t = 1023;
        aq = *(const bf16x8*)(Qts + ((size_t)(bh * SSZ + t)) * DN + quad * 8);
    }

    f32x4 acc0 = {0.f, 0.f, 0.f, 0.f};
    f32x4 acc1 = {0.f, 0.f, 0.f, 0.f};
    float lsum[4] = {0.f, 0.f, 0.f, 0.f};

    const int i_st = tid >> 2;
    const int d0 = (tid & 3) * 8;
    bf16x8 kreg = *(const bf16x8*)(Kts + ((size_t)(bh * SSZ + c0r * 64 + i_st)) * DN + d0);
    bf16x8 vreg = *(const bf16x8*)(Vts + ((size_t)(bh * SSZ + c0r * 64 + i_st)) * DN + d0);

    for (int c = c0r; c < c1r; c++) {
        __syncthreads();               // previous chunk consumed
        *(bf16x8*)&Ks[i_st][d0] = kreg;
        #pragma unroll
        for (int k2 = 0; k2 < 8; k2++) Vs[d0 + k2][i_st] = (unsigned short)vreg[k2];
        __syncthreads();
        if (c + 1 < c1r) {             // prefetch next chunk (overlaps compute)
            const size_t o = ((size_t)(bh * SSZ + (c + 1) * 64 + i_st)) * DN + d0;
            kreg = *(const bf16x8*)(Kts + o);
            vreg = *(const bf16x8*)(Vts + o);
        }

        const bool full = (c < qt);
        #pragma unroll
        for (int nt = 0; nt < 4; nt++) {
            const bf16x8 bk = *(const bf16x8*)&Ks[nt * 16 + col][quad * 8];
            f32x4 z = {0.f, 0.f, 0.f, 0.f};
            f32x4 raw = __builtin_amdgcn_mfma_f32_16x16x32_bf16(aq, bk, z, 0, 0, 0);
            const int il = nt * 16 + col;
            const int i_ = c * 64 + il;
            const float Epi = EpS[i_];
            const float Ppi = PpS[i_];
            const float fi = (float)i_;
            #pragma unroll
            for (int r = 0; r < 4; r++) {
                const float pdv = (tft[r] - fi) * (Ppt[r] - Ppi) * ((Ept[r] - Epi) * iEp[r]);
                const float sc  = raw[r] * __expf(nth * pdv);
                float p = __expf(sc);
                p = (full || il <= qrow[r]) ? p : 0.0f;
                lsum[r] += p;
                Ps[w][quad * 4 + r][il] = f2bf(p);
            }
        }
        #pragma unroll
        for (int ks = 0; ks < 2; ks++) {
            const bf16x8 ap = *(const bf16x8*)&Ps[w][col][ks * 32 + quad * 8];
            const bf16x8 bv0 = *(const bf16x8*)&Vs[col][ks * 32 + quad * 8];
            const bf16x8 bv1 = *(const bf16x8*)&Vs[16 + col][ks * 32 + quad * 8];
            acc0 = __builtin_amdgcn_mfma_f32_16x16x32_bf16(ap, bv0, acc0, 0, 0, 0);
            acc1 = __builtin_amdgcn_mfma_f32_16x16x32_bf16(ap, bv1, acc1, 0, 0, 0);
        }
    }

    // cross-lane partial-lsum totals (per row); store UNNORMALIZED partials
    #pragma unroll
    for (int r = 0; r < 4; r++) {
        float lr = lsum[r];
        #pragma unroll
        for (int msk = 8; msk >= 1; msk >>= 1) lr += __shfl_xor(lr, msk, 64);
        lsum[r] = lr;
    }
    const size_t cswh = (size_t)half * NROWS * EMBD;
    const size_t lsh  = (size_t)half * (HN * BSZ * SSZ) + ((size_t)bh << 10);
    #pragma unroll
    for (int r = 0; r < 4; r++) {
        if (tq[r] <= 1023) {
            float* dst = csw + cswh + ((size_t)(b * TQ + (tq[r] - 1))) * EMBD + h * DN;
            dst[col]      = acc0[r];
            dst[16 + col] = acc1[r];
            if (col == 0) ls[lsh + tq[r]] = lsum[r];
        }
    }
}

// ---------------------------------------------------------------------------
// Kernel 3: MLP via MFMA; now also combines the two attention partials:
// ctx = (csw0 + csw1) * 1/(ls0 + ls1), done in fp32 during feat staging.
// ---------------------------------------------------------------------------
__global__ __launch_bounds__(256)
void mlp3_kernel(const float* __restrict__ csw, const float* __restrict__ ls,
                 const float* __restrict__ ec,
                 const float* __restrict__ W1, const float* __restrict__ b1,
                 const float* __restrict__ W2, const float* __restrict__ b2,
                 float* __restrict__ out)
{
    __shared__ __align__(16) unsigned short featb[32][264];
    __shared__ __align__(16) unsigned short W1t[128][264];
    __shared__ float sred[4][16];

    const int tid = threadIdx.x;
    const int r0 = blockIdx.x * 32;
    const int w = tid >> 6, lane = tid & 63;
    const int quad = lane >> 4, col = lane & 15;
    const int mt = w & 1, nh = w >> 1;

    {
        const int jb = (tid & 31) * 4;
        const int ib = (tid >> 5) * 4;
        for (int ic = 0; ic < 8; ic++) {
            const int i0 = ic * 32 + ib;
            float rr[4][4];
            *(float4*)rr[0] = *(const float4*)(W1 + (size_t)(i0 + 0) * 128 + jb);
            *(float4*)rr[1] = *(const float4*)(W1 + (size_t)(i0 + 1) * 128 + jb);
            *(float4*)rr[2] = *(const float4*)(W1 + (size_t)(i0 + 2) * 128 + jb);
            *(float4*)rr[3] = *(const float4*)(W1 + (size_t)(i0 + 3) * 128 + jb);
            #pragma unroll
            for (int jj = 0; jj < 4; jj++) {
                bf16x4 v;
                v[0] = (short)f2bf(rr[0][jj]); v[1] = (short)f2bf(rr[1][jj]);
                v[2] = (short)f2bf(rr[2][jj]); v[3] = (short)f2bf(rr[3][jj]);
                *(bf16x4*)&W1t[jb + jj][i0] = v;
            }
        }
    }
    {
        const int rr = tid >> 3;
        const int c0 = (tid & 7) * 32;
        int row = r0 + rr; if (row >= NROWS) row = NROWS - 1;
        if (c0 < 128) {
            // ctx columns: combine the two KV-split partials + normalize
            const int bb = row / TQ;
            const int tt = row - bb * TQ + 1;
            const int hh = c0 >> 5;                 // one head per 32-col group
            const size_t lsi = ((size_t)(bb * HN + hh) << 10) + tt;
            const float l0 = ls[lsi];
            const float l1 = ls[(size_t)(HN * BSZ * SSZ) + lsi];
            const float inv = 1.0f / (l0 + l1);
            const float* s0 = csw + (size_t)row * EMBD + c0;
            const float* s1 = csw + (size_t)NROWS * EMBD + (size_t)row * EMBD + c0;
            #pragma unroll
            for (int g = 0; g < 4; g++) {
                float4 f0 = ((const float4*)s0)[g * 2];
                float4 f1 = ((const float4*)s0)[g * 2 + 1];
                const float4 g0 = ((const float4*)s1)[g * 2];
                const float4 g1 = ((const float4*)s1)[g * 2 + 1];
                f0.x = (f0.x + g0.x) * inv; f0.y = (f0.y + g0.y) * inv;
                f0.z = (f0.z + g0.z) * inv; f0.w = (f0.w + g0.w) * inv;
                f1.x = (f1.x + g1.x) * inv; f1.y = (f1.y + g1.y) * inv;
                f1.z = (f1.z + g1.z) * inv; f1.w = (f1.w + g1.w) * inv;
                *(bf16x8*)&featb[rr][c0 + g * 8] = cvt8(f0, f1);
            }
        } else {
            const int bb = row / TQ;
            const int tt = row - bb * TQ + 1;
            const float* src = ec + ((size_t)(bb * SSZ + tt)) * EMBD + (c0 - 128);
            #pragma unroll
            for (int g = 0; g < 4; g++) {
                const float4 f0 = ((const float4*)src)[g * 2];
                const float4 f1 = ((const float4*)src)[g * 2 + 1];
                *(bf16x8*)&featb[rr][c0 + g * 8] = cvt8(f0, f1);
            }
        }
    }
    __syncthreads();

    float s[4] = {0.f, 0.f, 0.f, 0.f};
    #pragma unroll
    for (int ntl = 0; ntl < 4; ntl++) {
        const int nt = nh * 4 + ntl;
        f32x4 acc = {0.f, 0.f, 0.f, 0.f};
        #pragma unroll
        for (int kc = 0; kc < 8; kc++) {
            const bf16x8 af = *(const bf16x8*)&featb[mt * 16 + col][kc * 32 + quad * 8];
            const bf16x8 bf = *(const bf16x8*)&W1t[nt * 16 + col][kc * 32 + quad * 8];
            acc = __builtin_amdgcn_mfma_f32_16x16x32_bf16(af, bf, acc, 0, 0, 0);
        }
        const int j = nt * 16 + col;
        const float b1j = b1[j], w2j = W2[j];
        #pragma unroll
        for (int r = 0; r < 4; r++)
            s[r] = fmaf(fmaxf(acc[r] + b1j, 0.0f), w2j, s[r]);
    }
    #pragma unroll
    for (int r = 0; r < 4; r++) {
        float sr = s[r];
        sr += __shfl_xor(sr, 1, 64);
        sr += __shfl_xor(sr, 2, 64);
        sr += __shfl_xor(sr, 4, 64);
        sr += __shfl_xor(sr, 8, 64);
        if (col == 0) sred[w][quad * 4 + r] = sr;
    }
    __syncthreads();
    if (tid < 32) {
        const int mt2 = tid >> 4, rr = tid & 15;
        const float logit = sred[mt2][rr] + sred[mt2 + 2][rr] + b2[0];
        const int grow = r0 + tid;
        if (grow < NROWS) {
            out[grow] = 1.0f / (1.0f + __expf(-logit));
            out[NROWS + grow] = 1.0f;
        }
    }
}

// ---------------------------------------------------------------------------
extern "C" void kernel_launch(void* const* d_in, const int* in_sizes, int n_in,
                              void* d_out, int out_size, void* d_ws, size_t ws_size,
                              hipStream_t stream)
{
    const int*   idx       = (const int*)d_in[0];
    const int*   flg       = (const int*)d_in[1];
    const float* gaps      = (const float*)d_in[2];
    const float* item_emb  = (const float*)d_in[3];
    const float* ans_emb   = (const float*)d_in[4];
    const float* Wq        = (const float*)d_in[5];
    const float* bq        = (const float*)d_in[6];
    const float* Wk        = (const float*)d_in[7];
    const float* bk        = (const float*)d_in[8];
    const float* Wv        = (const float*)d_in[9];
    const float* bv        = (const float*)d_in[10];
    const float* Wh        = (const float*)d_in[11];
    const float* bh        = (const float*)d_in[12];
    const float* W1        = (const float*)d_in[13];
    const float* b1        = (const float*)d_in[14];
    const float* W2        = (const float*)d_in[15];
    const float* b2        = (const float*)d_in[16];
    const float* theta_raw = (const float*)d_in[17];
    (void)in_sizes; (void)n_in; (void)ws_size;

    const size_t QKV = (size_t)BSZ * HN * SSZ * DN;   // 524288 elements
    unsigned short* Qts = (unsigned short*)d_ws;
    unsigned short* Kts = Qts + QKV;
    unsigned short* Vts = Kts + QKV;
    float* ec  = (float*)(Vts + QKV);                 // 3 MB offset, aligned
    float* srw = ec + (size_t)BSZ * SSZ * EMBD;
    float* csw = srw + (size_t)BSZ * HN * SSZ;        // 2 partial ctx buffers
    float* ls  = csw + 2 * (size_t)NROWS * EMBD;      // 2 partial lsum buffers

    float* out = (float*)d_out;

    embed4_kernel<<<BSZ * SSZ / 16, 256, 0, stream>>>(
        idx, flg, item_emb, ans_emb, Wq, bq, Wk, bk, Wv, bv, Wh, bh,
        Qts, Kts, Vts, ec, srw);
    attn4_kernel<<<BSZ * HN * 32, 256, 0, stream>>>(
        Qts, Kts, Vts, srw, gaps, theta_raw, csw, ls);
    mlp3_kernel<<<(NROWS + 31) / 32, 256, 0, stream>>>(
        csw, ls, ec, W1, b1, W2, b2, out);
}